// Round 1
// baseline (181099.329 us; speedup 1.0000x reference)
//
#include <hip/hip_runtime.h>
#include <cstddef>

typedef float f32x2 __attribute__((ext_vector_type(2)));

__device__ __forceinline__ float fast_tanh(float x) {
    // tanh(x) = (e^{2x}-1)/(e^{2x}+1); clamp to avoid inf/inf
    x = fminf(15.f, fmaxf(-15.f, x));
    float e = __expf(2.f * x);
    return (e - 1.f) * __builtin_amdgcn_rcpf(e + 1.f);
}

__global__ __launch_bounds__(256, 2)
void cnf_rk4_kernel(const float* __restrict__ x,
                    const float* __restrict__ ctx,
                    const float* __restrict__ eps,
                    const float* __restrict__ W1,
                    const float* __restrict__ b1,
                    const float* __restrict__ W2,
                    const float* __restrict__ b2,
                    const float* __restrict__ W3,
                    const float* __restrict__ b3,
                    float* __restrict__ out,
                    int nb)
{
    // W1 is [67][64]: rows 0,1 = z part, rows 2..65 = context part, row 66 = t.
    __shared__ __align__(16) float sW1z[2 * 64];
    __shared__ __align__(16) float sW1c[64 * 64];
    __shared__ __align__(16) float sW1t[64];
    __shared__ __align__(16) float sW2[64 * 64];    // [i][j] row-major (bwd: row i contiguous)
    __shared__ __align__(16) float sW2T[64 * 64];   // [j][i] (fwd: row j contiguous)
    __shared__ __align__(16) float sW3[128];        // [j][2]
    __shared__ __align__(16) float sb1[64];
    __shared__ __align__(16) float sb2[64];
    __shared__ float sb3[2];

    const int tid = threadIdx.x;
    for (int idx = tid; idx < 64 * 64; idx += 256) {
        sW1c[idx] = W1[(2 + (idx >> 6)) * 64 + (idx & 63)];
        float v = W2[idx];
        sW2[idx] = v;
        sW2T[(idx & 63) * 64 + (idx >> 6)] = v;
    }
    if (tid < 128) { sW1z[tid] = W1[tid]; sW3[tid] = W3[tid]; }
    if (tid >= 128 && tid < 192) sW1t[tid - 128] = W1[66 * 64 + (tid - 128)];
    if (tid >= 192) sb1[tid - 192] = b1[tid - 192];
    if (tid < 64) sb2[tid] = b2[tid];
    if (tid == 0) { sb3[0] = b3[0]; sb3[1] = b3[1]; }
    __syncthreads();

    const int s = blockIdx.x * 256 + tid;
    if (s >= nb) return;

    // c1 = b1 + ctx @ W1[2:66]  (context contribution is constant across all stages)
    float c1[64];
    #pragma unroll
    for (int j = 0; j < 64; ++j) c1[j] = sb1[j];
    const float* cp = ctx + (size_t)s * 64;
    #pragma unroll 1
    for (int m = 0; m < 64; ++m) {
        float cm = cp[m];
        const float* wr = sW1c + m * 64;
        #pragma unroll
        for (int j = 0; j < 64; ++j) c1[j] = __fmaf_rn(cm, wr[j], c1[j]);
    }

    float z0 = x[2 * s], z1 = x[2 * s + 1];
    float lp = 0.f;
    const float hstep = -1.f / 9.f;

    float h1v[64];
    float dv[64];

    #pragma unroll 1
    for (int k = 0; k < 9; ++k) {
        float ti = 1.f + (float)k * hstep;
        float ze0 = z0, ze1 = z1;
        float zs0 = 0.f, zs1 = 0.f, ls = 0.f;
        #pragma unroll 1
        for (int st = 0; st < 4; ++st) {
            float coef = (st == 0) ? 0.f : ((st == 3) ? 1.f : 0.5f);
            float tcur = ti + coef * hstep;
            const float* ep = eps + ((size_t)(k * 4 + st) * (size_t)nb + (size_t)s) * 2;
            float e0 = ep[0], e1 = ep[1];

            // layer 1: pre = c1 + ze0*W1[0] + ze1*W1[1] + t*W1[66]
            #pragma unroll
            for (int j = 0; j < 64; ++j) {
                float pre = c1[j];
                pre = __fmaf_rn(ze0, sW1z[j], pre);
                pre = __fmaf_rn(ze1, sW1z[64 + j], pre);
                pre = __fmaf_rn(tcur, sW1t[j], pre);
                h1v[j] = fast_tanh(pre);
            }

            // layer 2 fwd + layer 3 + backward seed d = (eps @ W3^T) * tanh'(a2)
            float f0 = sb3[0], f1 = sb3[1];
            #pragma unroll
            for (int j = 0; j < 64; ++j) {
                const f32x2* wr = (const f32x2*)(sW2T + j * 64);
                f32x2 acc = {0.f, 0.f};
                #pragma unroll
                for (int i = 0; i < 32; ++i) {
                    f32x2 hp = { h1v[2 * i], h1v[2 * i + 1] };
                    acc += hp * wr[i];
                }
                float a = acc.x + acc.y + sb2[j];
                float hj = fast_tanh(a);
                float w30 = sW3[2 * j], w31 = sW3[2 * j + 1];
                f0 = __fmaf_rn(hj, w30, f0);
                f1 = __fmaf_rn(hj, w31, f1);
                dv[j] = (e0 * w30 + e1 * w31) * (1.f - hj * hj);
            }

            // backward: d_h1 = W2 @ d, then through tanh' and z-rows of W1
            float g0 = 0.f, g1 = 0.f;
            #pragma unroll
            for (int i = 0; i < 64; ++i) {
                const f32x2* wr = (const f32x2*)(sW2 + i * 64);
                f32x2 acc = {0.f, 0.f};
                #pragma unroll
                for (int jj = 0; jj < 32; ++jj) {
                    f32x2 dp = { dv[2 * jj], dv[2 * jj + 1] };
                    acc += wr[jj] * dp;
                }
                float sder = (acc.x + acc.y) * (1.f - h1v[i] * h1v[i]);
                g0 = __fmaf_rn(sW1z[i], sder, g0);
                g1 = __fmaf_rn(sW1z[64 + i], sder, g1);
            }
            float negdiv = -(g0 * e0 + g1 * e1);

            float w = (st == 1 || st == 2) ? 2.f : 1.f;
            zs0 = __fmaf_rn(w, f0, zs0);
            zs1 = __fmaf_rn(w, f1, zs1);
            ls  = __fmaf_rn(w, negdiv, ls);
            if (st < 3) {
                float cn = (st == 2) ? 1.f : 0.5f;
                ze0 = __fmaf_rn(cn * hstep, f0, z0);
                ze1 = __fmaf_rn(cn * hstep, f1, z1);
            }
        }
        const float h6 = hstep * (1.f / 6.f);
        z0 = __fmaf_rn(h6, zs0, z0);
        z1 = __fmaf_rn(h6, zs1, z1);
        lp = __fmaf_rn(h6, ls, lp);
    }

    out[2 * s]     = z0;
    out[2 * s + 1] = z1;
    out[2 * nb + s] = lp;
}

extern "C" void kernel_launch(void* const* d_in, const int* in_sizes, int n_in,
                              void* d_out, int out_size, void* d_ws, size_t ws_size,
                              hipStream_t stream) {
    const float* x   = (const float*)d_in[0];
    const float* ctx = (const float*)d_in[1];
    const float* eps = (const float*)d_in[2];
    const float* W1  = (const float*)d_in[3];
    const float* b1  = (const float*)d_in[4];
    const float* W2  = (const float*)d_in[5];
    const float* b2  = (const float*)d_in[6];
    const float* W3  = (const float*)d_in[7];
    const float* b3  = (const float*)d_in[8];
    float* out = (float*)d_out;

    int nb = in_sizes[0] / 2;  // x is [B,2]
    int grid = (nb + 255) / 256;
    hipLaunchKernelGGL(cnf_rk4_kernel, dim3(grid), dim3(256), 0, stream,
                       x, ctx, eps, W1, b1, W2, b2, W3, b3, out, nb);
}